// Round 10
// baseline (219.728 us; speedup 1.0000x reference)
//
#include <hip/hip_runtime.h>
#include <hip/hip_bf16.h>
#include <stdint.h>

#define BATCH 8192
#define PEP 15
#define INC 512
#define OUTC 512
#define XROW (PEP*INC)          // 7680 floats per batch row
#define WT_P_ELEMS (INC*OUTC)   // 262144 bf16 per p
#define NSTEPS 16               // K = 512 = 16 x 32

typedef float f32x4 __attribute__((ext_vector_type(4)));
typedef short s16x8 __attribute__((ext_vector_type(8)));
typedef unsigned int u32x4 __attribute__((ext_vector_type(4)));

__device__ __forceinline__ ushort f2b(float v) {
  // round-to-nearest-even fp32 -> bf16 (host-side prep kernels)
  uint u = __float_as_uint(v);
  u += 0x7fffu + ((u >> 16) & 1u);
  return (ushort)(u >> 16);
}

__device__ __forceinline__ uint cvtpk(float a, float b) {
  // D[15:0]=bf16(a), D[31:16]=bf16(b); RNE. gfx950 has no builtin (T12 recipe).
  uint r;
  asm("v_cvt_pk_bf16_f32 %0, %1, %2" : "=v"(r) : "v"(a), "v"(b));
  return r;
}

// ---------------- kernel 1: W [p][k][n] fp32 -> fragment-linear bf16 (16x16x32) -------
// wt[(((p*16+ks)*32+n16)*64+l)*8+e] = bf16(W[p][ks*32+(l>>4)*8+e][n16*16+(l&15)])
// Per (ks,n16) the 64 lanes' 16B fragments are contiguous (1KB). Verified R1-R8.
__global__ __launch_bounds__(256) void wt_kernel(const float* __restrict__ w,
                                                 ushort* __restrict__ wt) {
  int gid = blockIdx.x * 256 + threadIdx.x;   // 15*16*32*64 = 491520 exactly
  int l   = gid & 63;
  int n16 = (gid >> 6) & 31;
  int ks  = (gid >> 11) & 15;
  int p   = gid >> 15;
  int fr = l & 15, g = l >> 4;
  const float* src = w + (size_t)p * WT_P_ELEMS + (size_t)(ks * 32 + g * 8) * OUTC + n16 * 16 + fr;
  s16x8 hv;
#pragma unroll
  for (int e = 0; e < 8; ++e) hv[e] = (short)f2b(src[(size_t)e * OUTC]);
  *(s16x8*)(wt + (size_t)gid * 8) = hv;
}

// ---------------- kernel 2: depth-3 counted-vmcnt GEMM --------------------------------
// Block = 4 waves, BM=64 x BN=256, BK=32; wave owns 64m x 64n.
// A and B staged fragment-linear via global_load_lds, TRIPLE-buffered:
// stage(ks+2) issued at iter top -> ~2 iterations of flight; vmcnt(12/6/0).
// R8-verified sync shape: vmcnt -> s_barrier -> ds_read/cvt/MFMA -> s_barrier.
__global__ __launch_bounds__(256, 2) void gemm_kernel(const float* __restrict__ x,
                                                      const ushort* __restrict__ wt,
                                                      const float* __restrict__ bias,
                                                      float* __restrict__ out) {
  __shared__ float  As[3][2048];    // 3 x 8KB : 4 m16-blocks x 2 halves x 64 lanes x 4 f32
  __shared__ ushort Bsh[3][8192];   // 3 x 16KB: 16 frag-blocks x 64 lanes x 8 bf16

  const int t    = threadIdx.x;
  const int lane = t & 63;
  const int wid  = t >> 6;
  const int fr   = lane & 15;
  const int g    = lane >> 4;

  // grid: 3840 = 8 xcd * 480; within XCD: j&1 = n-half (pairs adjacent -> x L2-share)
  const int bid  = blockIdx.x;
  const int xcd  = bid & 7;
  const int j    = bid >> 3;
  const int n2   = j & 1;
  const int pair = xcd * 240 + (j >> 1);   // 0..1919 = 128 m-blocks x 15 p
  const int mb   = pair & 127;
  const int p    = pair >> 7;
  const int m0   = mb * 64;

  // ---- A DMA sources (fragment-linear): wave wid stages m16-block wid, halves 0/1.
  const float* asrcA0 = x + (size_t)(m0 + wid * 16 + fr) * XROW + p * INC + g * 8;
  const float* asrcA1 = asrcA0 + 4;

  // ---- B DMA source: fragment-linear wt, n16 = n2*16 + wid*4 + q
  const ushort* bsrc = wt + (size_t)p * WT_P_ELEMS
                     + (size_t)(n2 * 16 + wid * 4) * 512 + (size_t)lane * 8;

  f32x4 acc[4][4] = {};             // [m16][nf]

  auto stage = [&](int ks, int buf) {
    __builtin_amdgcn_global_load_lds(
        (const __attribute__((address_space(1))) void*)(asrcA0 + ks * 32),
        (__attribute__((address_space(3))) void*)((char*)&As[buf][0] + wid * 2048 + lane * 16),
        16, 0, 0);
    __builtin_amdgcn_global_load_lds(
        (const __attribute__((address_space(1))) void*)(asrcA1 + ks * 32),
        (__attribute__((address_space(3))) void*)((char*)&As[buf][0] + wid * 2048 + 1024 + lane * 16),
        16, 0, 0);
#pragma unroll
    for (int q = 0; q < 4; ++q) {
      __builtin_amdgcn_global_load_lds(
          (const __attribute__((address_space(1))) void*)(bsrc + (size_t)ks * 16384 + q * 512),
          (__attribute__((address_space(3))) void*)(&Bsh[buf][(wid * 4 + q) * 512 + lane * 8]),
          16, 0, 0);
    }
  };

  // ---- prologue: fill pipeline 2 deep
  stage(0, 0);
  stage(1, 1);

#pragma unroll
  for (int ks = 0; ks < NSTEPS; ++ks) {
    const int cur = ks % 3;

    if (ks + 2 < NSTEPS) stage(ks + 2, (ks + 2) % 3);

    // counted wait: drain own stage(ks); keep stage(ks+1)+stage(ks+2) [12] in flight
    if (ks < 14)       asm volatile("s_waitcnt vmcnt(12)" ::: "memory");
    else if (ks == 14) asm volatile("s_waitcnt vmcnt(6)"  ::: "memory");
    else               asm volatile("s_waitcnt vmcnt(0)"  ::: "memory");
    __builtin_amdgcn_s_barrier();   // all waves' stage(ks) landed -> buf[cur] complete

    // A fragments: lane-contiguous 16B (conflict-free), cvt via v_cvt_pk_bf16_f32
    s16x8 af[4];
#pragma unroll
    for (int m16 = 0; m16 < 4; ++m16) {
      const char* ab = (const char*)&As[cur][0] + m16 * 2048 + lane * 16;
      f32x4 lo = *(const f32x4*)(ab);
      f32x4 hi = *(const f32x4*)(ab + 1024);
      u32x4 aw;
      aw[0] = cvtpk(lo[0], lo[1]); aw[1] = cvtpk(lo[2], lo[3]);
      aw[2] = cvtpk(hi[0], hi[1]); aw[3] = cvtpk(hi[2], hi[3]);
      af[m16] = __builtin_bit_cast(s16x8, aw);
    }

    // B fragments: lane-contiguous (conflict-free)
    s16x8 bf[4];
#pragma unroll
    for (int nf = 0; nf < 4; ++nf)
      bf[nf] = *(const s16x8*)&Bsh[cur][(wid * 4 + nf) * 512 + lane * 8];

#pragma unroll
    for (int m16 = 0; m16 < 4; ++m16)
#pragma unroll
      for (int nf = 0; nf < 4; ++nf)
        acc[m16][nf] = __builtin_amdgcn_mfma_f32_16x16x32_bf16(af[m16], bf[nf], acc[m16][nf], 0, 0, 0);

    __builtin_amdgcn_s_barrier();   // all reads done -> buf[(ks+3)%3] overwritable next iter
  }

  // ---- epilogue: wave-private LDS transpose (stride 68: conflict-free) -> full-line stores
  // C/D layout col=lane&15, row=(lane>>4)*4+r (m89-verified).
  const int n0 = n2 * 256 + wid * 64;
  float bv[4];
#pragma unroll
  for (int nf = 0; nf < 4; ++nf) bv[nf] = bias[p * OUTC + n0 + nf * 16 + fr];

  float* trans = reinterpret_cast<float*>(reinterpret_cast<char*>(&Bsh[0][0]) + wid * 8192); // 16x68 f32
  const int er = lane >> 4;          // 0..3
  const int ec = (lane & 15) * 4;    // 0..60

#pragma unroll
  for (int m16 = 0; m16 < 4; ++m16) {
    __builtin_amdgcn_sched_barrier(0);
#pragma unroll
    for (int nf = 0; nf < 4; ++nf)
#pragma unroll
      for (int r = 0; r < 4; ++r)
        trans[(g * 4 + r) * 68 + nf * 16 + fr] = acc[m16][nf][r] + bv[nf];
    __builtin_amdgcn_sched_barrier(0);
    asm volatile("s_waitcnt lgkmcnt(0)" ::: "memory");
    __builtin_amdgcn_sched_barrier(0);
    float* ob = out + (size_t)(m0 + m16 * 16) * XROW + p * INC + n0;
#pragma unroll
    for (int pass = 0; pass < 4; ++pass) {
      const int row = pass * 4 + er;
      f32x4 v = *(const f32x4*)&trans[row * 68 + ec];
      *(f32x4*)(ob + (size_t)row * XROW + ec) = v;
    }
    __builtin_amdgcn_sched_barrier(0);
    asm volatile("s_waitcnt lgkmcnt(0)" ::: "memory");   // reads landed before overwrite
    __builtin_amdgcn_sched_barrier(0);
  }
}

// ---------------- fallback (only if ws too small): naive fp32 ----------------
__global__ void naive_kernel(const float* __restrict__ x, const float* __restrict__ w,
                             const float* __restrict__ bias, float* __restrict__ out) {
  size_t i = (size_t)blockIdx.x * 256 + threadIdx.x;
  if (i >= (size_t)BATCH * PEP * OUTC) return;
  int o  = (int)(i & (OUTC - 1));
  int pp = (int)((i >> 9) % PEP);
  size_t b = i / ((size_t)PEP * OUTC);
  const float* xr = x + b * XROW + pp * INC;
  const float* wc = w + (size_t)pp * INC * OUTC + o;
  float s = bias[pp * OUTC + o];
  for (int k = 0; k < INC; ++k) s += xr[k] * wc[(size_t)k * OUTC];
  out[i] = s;
}

extern "C" void kernel_launch(void* const* d_in, const int* in_sizes, int n_in,
                              void* d_out, int out_size, void* d_ws, size_t ws_size,
                              hipStream_t stream) {
  const float* x    = (const float*)d_in[0];
  const float* w    = (const float*)d_in[1];
  const float* bias = (const float*)d_in[2];
  float* out = (float*)d_out;

  const size_t wt_bytes = (size_t)PEP * INC * OUTC * sizeof(ushort);  // 7.9 MB
  if (ws_size >= wt_bytes) {
    wt_kernel<<<1920, 256, 0, stream>>>(w, (ushort*)d_ws);
    gemm_kernel<<<3840, 256, 0, stream>>>(x, (const ushort*)d_ws, bias, out);
  } else {
    size_t total = (size_t)BATCH * PEP * OUTC;
    naive_kernel<<<(int)((total + 255) / 256), 256, 0, stream>>>(x, w, bias, out);
  }
}

// Round 11
// 166.996 us; speedup vs baseline: 1.3158x; 1.3158x over previous
//
#include <hip/hip_runtime.h>
#include <hip/hip_bf16.h>
#include <stdint.h>

#define BATCH 8192
#define PEP 15
#define INC 512
#define OUTC 512
#define XROW (PEP*INC)          // 7680 floats per batch row
#define WT_P_ELEMS (INC*OUTC)   // 262144 bf16 per p
#define NSTEPS 16               // K = 512 = 16 x 32

typedef float f32x4 __attribute__((ext_vector_type(4)));
typedef short s16x8 __attribute__((ext_vector_type(8)));
typedef unsigned int u32x4 __attribute__((ext_vector_type(4)));

__device__ __forceinline__ ushort f2b(float v) {
  // round-to-nearest-even fp32 -> bf16 (prep kernel)
  uint u = __float_as_uint(v);
  u += 0x7fffu + ((u >> 16) & 1u);
  return (ushort)(u >> 16);
}

__device__ __forceinline__ uint cvtpk(float a, float b) {
  // D[15:0]=bf16(a), D[31:16]=bf16(b); RNE. No builtin on gfx950 (T12 recipe).
  uint r;
  asm("v_cvt_pk_bf16_f32 %0, %1, %2" : "=v"(r) : "v"(a), "v"(b));
  return r;
}

// ---------------- kernel 1: W [p][k][n] fp32 -> fragment-linear bf16 (16x16x32) -------
// wt[(((p*16+ks)*32+n16)*64+l)*8+e] = bf16(W[p][ks*32+(l>>4)*8+e][n16*16+(l&15)])
// Per (ks,n16) the 64 lanes' 16B fragments are contiguous (1KB). Verified R1-R9.
__global__ __launch_bounds__(256) void wt_kernel(const float* __restrict__ w,
                                                 ushort* __restrict__ wt) {
  int gid = blockIdx.x * 256 + threadIdx.x;   // 15*16*32*64 = 491520 exactly
  int l   = gid & 63;
  int n16 = (gid >> 6) & 31;
  int ks  = (gid >> 11) & 15;
  int p   = gid >> 15;
  int fr = l & 15, g = l >> 4;
  const float* src = w + (size_t)p * WT_P_ELEMS + (size_t)(ks * 32 + g * 8) * OUTC + n16 * 16 + fr;
  s16x8 hv;
#pragma unroll
  for (int e = 0; e < 8; ++e) hv[e] = (short)f2b(src[(size_t)e * OUTC]);
  *(s16x8*)(wt + (size_t)gid * 8) = hv;
}

// ---------------- kernel 2: R7-shape GEMM, reg-staged bf16 A, 4 blocks/CU -------------
// Block = 4 waves, BM=64 x BN=256, BK=32; wave owns 64m x 64n.
// A: global f32 -> reg -> cvt_pk bf16 -> ds_write fragment-linear (once per element).
// B: global_load_lds fragment-linear (verified). Double-buffered, ONE __syncthreads
// per K-step at body end (m97 shape; compiler-managed waitcnt).
__global__ __launch_bounds__(256, 4) void gemm_kernel(const float* __restrict__ x,
                                                      const ushort* __restrict__ wt,
                                                      const float* __restrict__ bias,
                                                      float* __restrict__ out) {
  __shared__ ushort Ash[2][4][64][8];    // 2 x 4KB : [buf][m16][slot=fr+16g][8 bf16]
  __shared__ ushort Bsh[2][16][64][8];   // 2 x 16KB: [buf][n16][lane][8 bf16]

  const int t    = threadIdx.x;
  const int lane = t & 63;
  const int wid  = t >> 6;
  const int fr   = lane & 15;
  const int g    = lane >> 4;

  // grid: 3840 = 8 xcd * 480; within XCD: j&1 = n-half (pairs adjacent -> x L2-share)
  const int bid  = blockIdx.x;
  const int xcd  = bid & 7;
  const int j    = bid >> 3;
  const int n2   = j & 1;
  const int pair = xcd * 240 + (j >> 1);   // 0..1919 = 128 m-blocks x 15 p
  const int mb   = pair & 127;
  const int p    = pair >> 7;
  const int m0   = mb * 64;

  // ---- A reg-stage addressing: wave wid owns m16-block wid.
  //      thread: row_local ar = lane>>2 (0..15), k-group gq = lane&3 (8 floats).
  //      Global read: 4 consecutive lanes cover 128B of one row (coalesced).
  const int ar = lane >> 2;
  const int gq = lane & 3;
  const float* asrc = x + (size_t)(m0 + wid * 16 + ar) * XROW + p * INC + gq * 8;
  // LDS A dest slot = fr' + 16*g' with fr'=ar, g'=gq -> lane-contiguous frag reads.
  const int aslot = ar + 16 * gq;

  // ---- B DMA source: fragment-linear wt, n16 = n2*16 + wid*4 + q
  const ushort* bsrc = wt + (size_t)p * WT_P_ELEMS
                     + (size_t)(n2 * 16 + wid * 4) * 512 + (size_t)lane * 8;

  f32x4 acc[4][4] = {};             // [m16][nf]
  f32x4 pa0, pa1;                   // A staging regs (8 floats)

  auto cvt_store = [&](int buf) {
    u32x4 aw;
    aw[0] = cvtpk(pa0[0], pa0[1]); aw[1] = cvtpk(pa0[2], pa0[3]);
    aw[2] = cvtpk(pa1[0], pa1[1]); aw[3] = cvtpk(pa1[2], pa1[3]);
    *(u32x4*)&Ash[buf][wid][aslot][0] = aw;
  };
  auto stageB = [&](int ks, int buf) {
#pragma unroll
    for (int q = 0; q < 4; ++q) {
      __builtin_amdgcn_global_load_lds(
          (const __attribute__((address_space(1))) void*)(bsrc + (size_t)ks * 16384 + q * 512),
          (__attribute__((address_space(3))) void*)(&Bsh[buf][wid * 4 + q][lane][0]),
          16, 0, 0);
    }
  };

  // ---- prologue: A(0) -> LDS, B(0) DMA, A(1) -> regs
  pa0 = *(const f32x4*)(asrc);
  pa1 = *(const f32x4*)(asrc + 4);
  cvt_store(0);
  stageB(0, 0);
  pa0 = *(const f32x4*)(asrc + 32);
  pa1 = *(const f32x4*)(asrc + 36);
  __syncthreads();

#pragma unroll
  for (int ks = 0; ks < NSTEPS; ++ks) {
    const int cur = ks & 1;
    const int nxt = cur ^ 1;

    // stage(ks+1) into nxt: A from regs (cvt once), B via DMA
    if (ks + 1 < NSTEPS) {
      cvt_store(nxt);
      stageB(ks + 1, nxt);
    }
    // refill A regs for ks+2 (flies through ds_read+MFMA, drained at barrier)
    if (ks + 2 < NSTEPS) {
      pa0 = *(const f32x4*)(asrc + (ks + 2) * 32);
      pa1 = *(const f32x4*)(asrc + (ks + 2) * 32 + 4);
    }

    // A fragments: lane-contiguous 16B, already bf16 -> direct MFMA operands
    s16x8 af[4];
#pragma unroll
    for (int m16 = 0; m16 < 4; ++m16)
      af[m16] = *(const s16x8*)&Ash[cur][m16][lane][0];

    // B fragments: lane-contiguous (conflict-free)
    s16x8 bf[4];
#pragma unroll
    for (int nf = 0; nf < 4; ++nf)
      bf[nf] = *(const s16x8*)&Bsh[cur][wid * 4 + nf][lane][0];

#pragma unroll
    for (int m16 = 0; m16 < 4; ++m16)
#pragma unroll
      for (int nf = 0; nf < 4; ++nf)
        acc[m16][nf] = __builtin_amdgcn_mfma_f32_16x16x32_bf16(af[m16], bf[nf], acc[m16][nf], 0, 0, 0);

    __syncthreads();   // single drain point per K-step (m97 shape)
  }

  // ---- epilogue: wave-private LDS transpose (stride 68: conflict-free) -> full-line stores
  // C/D layout col=lane&15, row=(lane>>4)*4+r (m89-verified).
  const int n0 = n2 * 256 + wid * 64;
  float bv[4];
#pragma unroll
  for (int nf = 0; nf < 4; ++nf) bv[nf] = bias[p * OUTC + n0 + nf * 16 + fr];

  float* trans = reinterpret_cast<float*>(reinterpret_cast<char*>(&Bsh[0][0][0][0]) + wid * 8192); // 16x68 f32
  const int er = lane >> 4;          // 0..3
  const int ec = (lane & 15) * 4;    // 0..60

#pragma unroll
  for (int m16 = 0; m16 < 4; ++m16) {
    __builtin_amdgcn_sched_barrier(0);
#pragma unroll
    for (int nf = 0; nf < 4; ++nf)
#pragma unroll
      for (int r = 0; r < 4; ++r)
        trans[(g * 4 + r) * 68 + nf * 16 + fr] = acc[m16][nf][r] + bv[nf];
    __builtin_amdgcn_sched_barrier(0);
    asm volatile("s_waitcnt lgkmcnt(0)" ::: "memory");
    __builtin_amdgcn_sched_barrier(0);
    float* ob = out + (size_t)(m0 + m16 * 16) * XROW + p * INC + n0;
#pragma unroll
    for (int pass = 0; pass < 4; ++pass) {
      const int row = pass * 4 + er;
      f32x4 v = *(const f32x4*)&trans[row * 68 + ec];
      *(f32x4*)(ob + (size_t)row * XROW + ec) = v;
    }
    __builtin_amdgcn_sched_barrier(0);
    asm volatile("s_waitcnt lgkmcnt(0)" ::: "memory");   // reads landed before overwrite
    __builtin_amdgcn_sched_barrier(0);
  }
}

// ---------------- fallback (only if ws too small): naive fp32 ----------------
__global__ void naive_kernel(const float* __restrict__ x, const float* __restrict__ w,
                             const float* __restrict__ bias, float* __restrict__ out) {
  size_t i = (size_t)blockIdx.x * 256 + threadIdx.x;
  if (i >= (size_t)BATCH * PEP * OUTC) return;
  int o  = (int)(i & (OUTC - 1));
  int pp = (int)((i >> 9) % PEP);
  size_t b = i / ((size_t)PEP * OUTC);
  const float* xr = x + b * XROW + pp * INC;
  const float* wc = w + (size_t)pp * INC * OUTC + o;
  float s = bias[pp * OUTC + o];
  for (int k = 0; k < INC; ++k) s += xr[k] * wc[(size_t)k * OUTC];
  out[i] = s;
}

extern "C" void kernel_launch(void* const* d_in, const int* in_sizes, int n_in,
                              void* d_out, int out_size, void* d_ws, size_t ws_size,
                              hipStream_t stream) {
  const float* x    = (const float*)d_in[0];
  const float* w    = (const float*)d_in[1];
  const float* bias = (const float*)d_in[2];
  float* out = (float*)d_out;

  const size_t wt_bytes = (size_t)PEP * INC * OUTC * sizeof(ushort);  // 7.9 MB
  if (ws_size >= wt_bytes) {
    wt_kernel<<<1920, 256, 0, stream>>>(w, (ushort*)d_ws);
    gemm_kernel<<<3840, 256, 0, stream>>>(x, (const ushort*)d_ws, bias, out);
  } else {
    size_t total = (size_t)BATCH * PEP * OUTC;
    naive_kernel<<<(int)((total + 255) / 256), 256, 0, stream>>>(x, w, bias, out);
  }
}